// Round 11
// baseline (344.849 us; speedup 1.0000x reference)
//
#include <hip/hip_runtime.h>

typedef __bf16 bf16x8 __attribute__((ext_vector_type(8)));
typedef __bf16 bf16x4 __attribute__((ext_vector_type(4)));
typedef float  f32x4  __attribute__((ext_vector_type(4)));
typedef float  f32x16 __attribute__((ext_vector_type(16)));

#define DEVI __device__ __forceinline__

DEVI bf16x8 ld8(const __bf16* p) { return *reinterpret_cast<const bf16x8*>(p); }
DEVI f32x4 mfma16(bf16x8 a, bf16x8 b, f32x4 c) {
  return __builtin_amdgcn_mfma_f32_16x16x32_bf16(a, b, c, 0, 0, 0);
}
DEVI f32x16 mfma32(bf16x8 a, bf16x8 b, f32x16 c) {
  return __builtin_amdgcn_mfma_f32_32x32x16_bf16(a, b, c, 0, 0, 0);
}
DEVI void gl_lds16(const void* g, void* l) {
  __builtin_amdgcn_global_load_lds((__attribute__((address_space(1))) void*)g,
                                   (__attribute__((address_space(3))) void*)l, 16, 0, 0);
}
DEVI unsigned pk2(float a, float b) {
  union { __bf16 h[2]; unsigned u; } x;
  x.h[0] = (__bf16)a; x.h[1] = (__bf16)b; return x.u;
}

#if __has_builtin(__builtin_amdgcn_exp2f)
#define EXP2(x) __builtin_amdgcn_exp2f(x)
#else
#define EXP2(x) exp2f(x)
#endif

// ---------- x fp32 -> bf16 ----------
__global__ void k_cvt(const float* __restrict__ in, __bf16* __restrict__ out, int n4) {
  int i = blockIdx.x * blockDim.x + threadIdx.x;
  if (i >= n4) return;
  f32x4 v = reinterpret_cast<const f32x4*>(in)[i];
  bf16x4 o;
  o[0] = (__bf16)v[0]; o[1] = (__bf16)v[1]; o[2] = (__bf16)v[2]; o[3] = (__bf16)v[3];
  reinterpret_cast<bf16x4*>(out)[i] = o;
}

// ---------- transpose fp32 [R][C] -> bf16 [C][R] (optionally hi+lo split) ----------
template<bool LO>
__global__ void k_tr(const float* __restrict__ in, __bf16* __restrict__ oh,
                     __bf16* __restrict__ ol, int R, int C) {
  __shared__ float t[32][33];
  const float* im = in + (size_t)blockIdx.z * R * C;
  __bf16* ohm = oh + (size_t)blockIdx.z * R * C;
  __bf16* olm = LO ? (ol + (size_t)blockIdx.z * R * C) : nullptr;
  int c0 = blockIdx.x * 32, r0 = blockIdx.y * 32;
  int tx = threadIdx.x & 31, ty = threadIdx.x >> 5;
  #pragma unroll
  for (int k = 0; k < 32; k += 8)
    t[ty + k][tx] = im[(size_t)(r0 + ty + k) * C + c0 + tx];
  __syncthreads();
  #pragma unroll
  for (int k = 0; k < 32; k += 8) {
    float v = t[tx][ty + k];
    size_t o = (size_t)(c0 + ty + k) * R + r0 + tx;
    __bf16 h = (__bf16)v;
    ohm[o] = h;
    if (LO) olm[o] = (__bf16)(v - (float)h);
  }
}

// ---------- QKV projection v2: swapped operands for Q/K -> bf16x4 stores ----------
__global__ __launch_bounds__(256) void k_qkv(
    const __bf16* __restrict__ xb, const __bf16* __restrict__ Wt,
    const float* __restrict__ bq, const float* __restrict__ bk, const float* __restrict__ bv,
    __bf16* __restrict__ Qb, __bf16* __restrict__ Kb, __bf16* __restrict__ Vtb) {
  const int w = threadIdx.x >> 6, lane = threadIdx.x & 63;
  const int g = lane >> 4, qc = lane & 15;
  const int which = blockIdx.z >> 3, h = blockIdx.z & 7;
  const int s_blk = blockIdx.x * 64;
  const int e_blk = blockIdx.y * 64;
  const __bf16* Wm = Wt + ((size_t)blockIdx.z << 16);
  const float* bias = (which == 0 ? bq : which == 1 ? bk : bv) + h * 256;
  const int b = s_blk >> 11, s0 = s_blk & 2047;
  const int bh = b * 8 + h;

  if (which == 2) {
    // V path (original orientation): C[s-rows][e-col], writes Vt[e][s] as bf16x4
    const int m0 = s_blk + w * 16;
    f32x4 acc[4] = {};
    const __bf16* ap = xb + (m0 + qc) * 256 + g * 8;
    #pragma unroll
    for (int kk = 0; kk < 8; kk++) {
      bf16x8 af = ld8(ap + kk * 32);
      #pragma unroll
      for (int nt = 0; nt < 4; nt++) {
        bf16x8 bf = ld8(Wm + (e_blk + nt * 16 + qc) * 256 + kk * 32 + g * 8);
        acc[nt] = mfma16(af, bf, acc[nt]);
      }
    }
    const int sm = (m0 & 2047);
    #pragma unroll
    for (int nt = 0; nt < 4; nt++) {
      const int e = e_blk + nt * 16 + qc;
      const float be = bias[e];
      bf16x4 pk;
      #pragma unroll
      for (int r = 0; r < 4; r++) pk[r] = (__bf16)(acc[nt][r] + be);
      *reinterpret_cast<bf16x4*>(Vtb + ((bh * 256 + e) * 2048 + sm + g * 4)) = pk;
    }
  } else {
    // Q/K path (swapped): A=W (e-dim), B=x (s-dim) -> C[e-rows][s-col];
    // thread owns 4 consecutive e at fixed s -> bf16x4 coalesced store.
    const int e0 = e_blk + w * 16;
    f32x4 acc[4] = {};
    const __bf16* wp = Wm + (e0 + qc) * 256 + g * 8;
    #pragma unroll
    for (int kk = 0; kk < 8; kk++) {
      bf16x8 af = ld8(wp + kk * 32);
      #pragma unroll
      for (int st = 0; st < 4; st++) {
        bf16x8 bf = ld8(xb + (s_blk + st * 16 + qc) * 256 + kk * 32 + g * 8);
        acc[st] = mfma16(af, bf, acc[st]);
      }
    }
    // Q folds 1/sqrt(D) * log2(e)  (attention runs in exp2 domain)
    const float sc = (which == 0) ? 0.0625f * 1.4426950408889634f : 1.0f;
    __bf16* Out = (which == 0) ? Qb : Kb;
    float be[4];
    #pragma unroll
    for (int r = 0; r < 4; r++) be[r] = bias[e0 + g * 4 + r];
    #pragma unroll
    for (int st = 0; st < 4; st++) {
      const int srow = s0 + st * 16 + qc;
      bf16x4 pk;
      #pragma unroll
      for (int r = 0; r < 4; r++) pk[r] = (__bf16)((acc[st][r] + be[r]) * sc);
      *reinterpret_cast<bf16x4*>(Out + ((size_t)(bh * 2048 + srow)) * 256 + e0 + g * 4) = pk;
    }
  }
}

// ---------- flash attention v10: R10 structure + R6-proven 64B-granule V layout ----------
// grid 256 blocks x 256 thr (16bh x 16qt), full kv per block, 32 double-buffered
// 64-kv tiles, 128KB LDS. V tile: unit 64B, offset = (d>>3)*1024 + kvh*512 +
// (d&7)*64 + (ci^((d>>3)&3))*16  — bank structure identical to R6 (0 conflicts).
__global__ __launch_bounds__(256) void k_attn(
    const __bf16* __restrict__ Qb, const __bf16* __restrict__ Kb,
    const __bf16* __restrict__ Vtb, __bf16* __restrict__ Oh, __bf16* __restrict__ Ol) {
  __shared__ __align__(16) unsigned char smem[131072];
  const int tid = threadIdx.x;
  const int wl = tid >> 6, lane = tid & 63;
  const int hi = lane >> 5, q = lane & 31;

  const int bid = blockIdx.x;
  const int s = (bid & 7) * 32 + (bid >> 3);      // XCD-chunked swizzle (bijective)
  const int bh = s >> 4, qt = s & 15;

  const int q0w = qt * 128 + wl * 32;
  const char* Kg = (const char*)Kb + ((size_t)bh * 2048) * 512;
  const char* Vg = (const char*)Vtb + (size_t)bh * 256 * 4096;
  const __bf16* Qp = Qb + ((size_t)(bh * 2048 + q0w + q)) * 256;

  bf16x8 qf[16];
  #pragma unroll
  for (int kk = 0; kk < 16; kk++) qf[kk] = ld8(Qp + kk * 16 + hi * 8);

  f32x16 acc[8];
  #pragma unroll
  for (int i = 0; i < 8; i++)
    #pragma unroll
    for (int e = 0; e < 16; e++) acc[i][e] = 0.f;

  // stage one 64-kv tile: K 32KB ([64 kv][512B], 4-bit XOR swz) +
  // V 32KB (64B units: [32 sb][2 kvh][8 dlo], 2-bit XOR on 16B chunk)
  auto stage = [&](int nb, int t) {
    unsigned char* kbp = smem + nb * 32768 + wl * 8192;
    unsigned char* vbp = smem + 65536 + nb * 32768 + wl * 8192;
    #pragma unroll
    for (int j = 0; j < 8; j++) {
      const int O = wl * 8192 + j * 1024 + lane * 16;
      const int kv = O >> 9;
      const int c = ((O >> 4) & 31) ^ (kv & 15);
      gl_lds16(Kg + (size_t)t * 32768 + (size_t)kv * 512 + c * 16, kbp + j * 1024);
    }
    #pragma unroll
    for (int j = 0; j < 8; j++) {
      const int O = wl * 8192 + j * 1024 + lane * 16;
      const int sb = O >> 10;
      const int kvh = (O >> 9) & 1;
      const int dlo = (O >> 6) & 7;
      const int ci = (O >> 4) & 3;
      const int d = sb * 8 + dlo;
      gl_lds16(Vg + (size_t)d * 4096 + (size_t)t * 128 + kvh * 64 + ((ci ^ (sb & 3)) << 4),
               vbp + j * 1024);
    }
  };

  float m_run = -3.0e38f, l_run = 0.f;
  stage(0, 0);
  __syncthreads();

  for (int t = 0; t < 32; t++) {
    const int cur = t & 1;
    const unsigned char* kbc = smem + cur * 32768;
    const unsigned char* vbc = smem + 65536 + cur * 32768;
    if (t < 31) stage(cur ^ 1, t + 1);

    // ---- QK^T (swapped): two independent 16-MFMA chains (kv rows q, 32+q) ----
    f32x16 st0, st1;
    #pragma unroll
    for (int e = 0; e < 16; e++) { st0[e] = 0.f; st1[e] = 0.f; }
    __builtin_amdgcn_s_setprio(1);
    #pragma unroll
    for (int kk = 0; kk < 16; kk++) {
      const int o0 = q * 512 + ((((kk << 1) + hi) ^ (q & 15)) << 4);
      bf16x8 k0 = *reinterpret_cast<const bf16x8*>(kbc + o0);
      bf16x8 k1 = *reinterpret_cast<const bf16x8*>(kbc + o0 + 16384);
      st0 = mfma32(k0, qf[kk], st0);
      st1 = mfma32(k1, qf[kk], st1);
    }
    __builtin_amdgcn_s_setprio(0);

    // ---- online softmax over 64 values, exp2 domain, defer-max THR=8 ----
    f32x16 mx;
    #pragma unroll
    for (int r = 0; r < 16; r++) mx[r] = fmaxf(st0[r], st1[r]);
    #pragma unroll
    for (int w2 = 8; w2 > 0; w2 >>= 1)
      #pragma unroll
      for (int r = 0; r < w2; r++) mx[r] = fmaxf(mx[r], mx[r + w2]);
    const float rmax = fmaxf(mx[0], __shfl_xor(mx[0], 32));
    if (__any(rmax > m_run + 8.0f)) {
      const float m_new = fmaxf(rmax, m_run);
      const float alpha = EXP2(m_run - m_new);
      m_run = m_new;
      l_run *= alpha;
      #pragma unroll
      for (int r = 0; r < 16; r++) {
        const float ar = __shfl(alpha, (r & 3) + 8 * (r >> 2) + 4 * hi);
        #pragma unroll
        for (int dt = 0; dt < 8; dt++) acc[dt][r] *= ar;
      }
    }
    f32x16 sm_;
    #pragma unroll
    for (int r = 0; r < 16; r++) {
      st0[r] = EXP2(st0[r] - m_run);
      st1[r] = EXP2(st1[r] - m_run);
      sm_[r] = st0[r] + st1[r];
    }
    #pragma unroll
    for (int w2 = 8; w2 > 0; w2 >>= 1)
      #pragma unroll
      for (int r = 0; r < w2; r++) sm_[r] += sm_[r + w2];
    l_run += sm_[0] + __shfl_xor(sm_[0], 32);

    // ---- P -> 4 PV A-frags in-register (pk2 + shfl_xor exchange, R7-proven) ----
    bf16x8 pa[4];
    #define MKCHUNK(STV, H2, OUT) {                          \
      const unsigned L0 = pk2(STV[H2 * 8 + 0], STV[H2 * 8 + 1]);  \
      const unsigned L1 = pk2(STV[H2 * 8 + 2], STV[H2 * 8 + 3]);  \
      const unsigned H0 = pk2(STV[H2 * 8 + 4], STV[H2 * 8 + 5]);  \
      const unsigned H1 = pk2(STV[H2 * 8 + 6], STV[H2 * 8 + 7]);  \
      const unsigned xL0 = __shfl_xor(L0, 32), xL1 = __shfl_xor(L1, 32); \
      const unsigned xH0 = __shfl_xor(H0, 32), xH1 = __shfl_xor(H1, 32); \
      unsigned pw[4];                                        \
      pw[0] = hi ? xH0 : L0;  pw[1] = hi ? xH1 : L1;         \
      pw[2] = hi ? H0 : xL0;  pw[3] = hi ? H1 : xL1;         \
      OUT = *reinterpret_cast<bf16x8*>(pw); }
    MKCHUNK(st0, 0, pa[0]); MKCHUNK(st0, 1, pa[1]);
    MKCHUNK(st1, 0, pa[2]); MKCHUNK(st1, 1, pa[3]);
    #undef MKCHUNK

    // ---- PV: acc[dt] col=d=dt*32+q ----
    __builtin_amdgcn_s_setprio(1);
    #pragma unroll
    for (int dt = 0; dt < 8; dt++) {
      const int d = dt * 32 + q;
      const int base = (d >> 3) * 1024 + (d & 7) * 64;
      const int key = (d >> 3) & 3;
      #pragma unroll
      for (int c = 0; c < 4; c++) {
        const int off = base + (c >> 1) * 512 +
                        (((((c & 1) << 1) | hi) ^ key) << 4);
        bf16x8 vf = *reinterpret_cast<const bf16x8*>(vbc + off);
        acc[dt] = mfma32(pa[c], vf, acc[dt]);
      }
    }
    __builtin_amdgcn_s_setprio(0);
    __syncthreads();
  }

  // ---- epilogue: divide by l, split hi/lo bf16 ----
  float linv[16];
  #pragma unroll
  for (int r = 0; r < 16; r++)
    linv[r] = 1.f / __shfl(l_run, (r & 3) + 8 * (r >> 2) + 4 * hi);
  const int b = bh >> 3, h = bh & 7;
  #pragma unroll
  for (int dt = 0; dt < 8; dt++) {
    #pragma unroll
    for (int r = 0; r < 16; r++) {
      const float v = acc[dt][r] * linv[r];
      const int qrow = (r & 3) + 8 * (r >> 2) + 4 * hi;
      const size_t off = (size_t)b * (2048 * 2048) +
                         (size_t)(q0w + qrow) * 2048 + h * 256 + dt * 32 + q;
      const __bf16 hv = (__bf16)v;
      Oh[off] = hv;
      Ol[off] = (__bf16)(v - (float)hv);
    }
  }
}

// ---------- output projection v2: swapped operands, full K per block, NO atomics ----------
// grid (64 m-tiles, 4 n-tiles) x 256 thr. Wave w owns n-subtile 16; thread owns
// 4 consecutive n at fixed m -> f32x4 stores. Terms: Wh*Oh + Wh*Ol + Wl*Oh.
__global__ __launch_bounds__(256) void k_out(
    const __bf16* __restrict__ Oh, const __bf16* __restrict__ Ol,
    const __bf16* __restrict__ Wh, const __bf16* __restrict__ Wl,
    const float* __restrict__ bo, float* __restrict__ out) {
  const int w = threadIdx.x >> 6, lane = threadIdx.x & 63;
  const int g = lane >> 4, qc = lane & 15;
  const int m_blk = blockIdx.x * 64;
  const int n0w = blockIdx.y * 64 + w * 16;
  f32x4 acc[4] = {};
  const __bf16* wh_p = Wh + (size_t)(n0w + qc) * 2048 + g * 8;
  const __bf16* wl_p = Wl + (size_t)(n0w + qc) * 2048 + g * 8;
  for (int kk = 0; kk < 64; kk++) {
    bf16x8 whf = ld8(wh_p + kk * 32);
    bf16x8 wlf = ld8(wl_p + kk * 32);
    #pragma unroll
    for (int st = 0; st < 4; st++) {
      const size_t arow = (size_t)(m_blk + st * 16 + qc) * 2048 + kk * 32 + g * 8;
      bf16x8 ah = ld8(Oh + arow);
      bf16x8 al = ld8(Ol + arow);
      acc[st] = mfma16(whf, ah, acc[st]);
      acc[st] = mfma16(whf, al, acc[st]);
      acc[st] = mfma16(wlf, ah, acc[st]);
    }
  }
  float bob[4];
  #pragma unroll
  for (int r = 0; r < 4; r++) bob[r] = bo[n0w + g * 4 + r];
  #pragma unroll
  for (int st = 0; st < 4; st++) {
    const int m = m_blk + st * 16 + qc;
    f32x4 px;
    #pragma unroll
    for (int r = 0; r < 4; r++) px[r] = acc[st][r] + bob[r];
    *reinterpret_cast<f32x4*>(out + (size_t)m * 256 + n0w + g * 4) = px;
  }
}

extern "C" void kernel_launch(void* const* d_in, const int* in_sizes, int n_in,
                              void* d_out, int out_size, void* d_ws, size_t ws_size,
                              hipStream_t stream) {
  const float* x  = (const float*)d_in[0];
  const float* Wq = (const float*)d_in[1];
  const float* bq = (const float*)d_in[2];
  const float* Wk = (const float*)d_in[3];
  const float* bk = (const float*)d_in[4];
  const float* Wv = (const float*)d_in[5];
  const float* bv = (const float*)d_in[6];
  const float* Wo = (const float*)d_in[7];
  const float* bo = (const float*)d_in[8];
  char* p = (char*)d_ws;
  __bf16* xb  = (__bf16*)(p);                          // 2 MB  [4096][256]
  __bf16* Wt  = (__bf16*)(p + (2ull  << 20));          // 3 MB  [3][8][256 e][256 d]
  __bf16* Woh = (__bf16*)(p + (5ull  << 20));          // 1 MB  [256 n][2048 k]
  __bf16* Wol = (__bf16*)(p + (6ull  << 20));          // 1 MB
  __bf16* Qb  = (__bf16*)(p + (7ull  << 20));          // 16 MB [bh][s][d] (scale folded)
  __bf16* Kb  = (__bf16*)(p + (23ull << 20));          // 16 MB [bh][s][d]
  __bf16* Vtb = (__bf16*)(p + (39ull << 20));          // 16 MB [bh][d][s]
  __bf16* Ohb = (__bf16*)(p + (55ull << 20));          // 16 MB [bs][h*d] hi
  __bf16* Olb = (__bf16*)(p + (71ull << 20));          // 16 MB [bs][h*d] lo

  k_cvt<<<dim3(1024), dim3(256), 0, stream>>>(x, xb, 262144);
  k_tr<false><<<dim3(8, 8, 8),  dim3(256), 0, stream>>>(Wq, Wt + 0 * 524288, nullptr, 256, 256);
  k_tr<false><<<dim3(8, 8, 8),  dim3(256), 0, stream>>>(Wk, Wt + 1 * 524288, nullptr, 256, 256);
  k_tr<false><<<dim3(8, 8, 8),  dim3(256), 0, stream>>>(Wv, Wt + 2 * 524288, nullptr, 256, 256);
  k_tr<true ><<<dim3(8, 64, 1), dim3(256), 0, stream>>>(Wo, Woh, Wol, 2048, 256);
  k_qkv<<<dim3(64, 4, 24), dim3(256), 0, stream>>>(xb, Wt, bq, bk, bv, Qb, Kb, Vtb);
  k_attn<<<dim3(256), dim3(256), 0, stream>>>(Qb, Kb, Vtb, Ohb, Olb);
  k_out<<<dim3(64, 4), dim3(256), 0, stream>>>(Ohb, Olb, Woh, Wol, bo, (float*)d_out);
}